// Round 1
// baseline (4338.274 us; speedup 1.0000x reference)
//
#include <hip/hip_runtime.h>
#include <hip/hip_bf16.h>
#include <math.h>

#define N_NODES 100000
#define N_EDGES 1600000
#define N_GRAPHS 256
#define IN_DIM 128
#define F_SIZE 64
#define OUT_DIM 10

// ---------------- degree / norm ----------------

__global__ void k_fill_deg(float* __restrict__ deg, int n) {
    int i = blockIdx.x * blockDim.x + threadIdx.x;
    if (i < n) deg[i] = 1.0f;  // self-loop weight
}

__global__ void k_deg(const float* __restrict__ ew, const int* __restrict__ dst,
                      float* __restrict__ deg, int e) {
    int i = blockIdx.x * blockDim.x + threadIdx.x;
    if (i < e) atomicAdd(&deg[dst[i]], fabsf(ew[i]));
}

__global__ void k_dinv(float* __restrict__ deg, float* __restrict__ selfnorm, int n) {
    int i = blockIdx.x * blockDim.x + threadIdx.x;
    if (i < n) {
        float d = deg[i];
        float di = (d > 0.f) ? (1.0f / sqrtf(d)) : 0.f;
        deg[i] = di;          // deg now holds dinv
        selfnorm[i] = di * di;
    }
}

__global__ void k_norm(const float* __restrict__ ew, const int* __restrict__ src,
                       const int* __restrict__ dst, const float* __restrict__ dinv,
                       float* __restrict__ norm, int e) {
    int i = blockIdx.x * blockDim.x + threadIdx.x;
    if (i < e) norm[i] = dinv[src[i]] * fabsf(ew[i]) * dinv[dst[i]];
}

// ---------------- GEMM: H[n][64] = X[n][K] @ W[K][64] ----------------
// 32 nodes per block, 256 threads; thread = (node nl = tid>>3, colgroup cg = tid&7 -> 8 cols)

template <int K>
__global__ __launch_bounds__(256) void k_gemm(const float* __restrict__ X,
                                              const float* __restrict__ W,
                                              float* __restrict__ H, int n) {
    __shared__ __align__(16) float Ws[K * 64];
    __shared__ float Xs[32 * (K + 2)];
    const int tid = threadIdx.x;
    const int n0 = blockIdx.x * 32;

    // stage W (K*64 floats) as float4, coalesced
    for (int i = tid; i < K * 16; i += 256) {
        ((float4*)Ws)[i] = ((const float4*)W)[i];
    }
    // stage X tile (32 rows x K floats), padded stride K+2
    for (int i = tid; i < 32 * (K / 4); i += 256) {
        const int r = i / (K / 4);
        const int c = i % (K / 4);
        const float4 v = ((const float4*)(X + (size_t)(n0 + r) * K))[c];
        float* p = &Xs[r * (K + 2) + c * 4];
        p[0] = v.x; p[1] = v.y; p[2] = v.z; p[3] = v.w;
    }
    __syncthreads();

    const int nl = tid >> 3;
    const int cg = tid & 7;
    float acc[8];
#pragma unroll
    for (int j = 0; j < 8; ++j) acc[j] = 0.f;

#pragma unroll 4
    for (int k = 0; k < K; ++k) {
        const float xv = Xs[nl * (K + 2) + k];
        const float4 w0 = *(const float4*)&Ws[k * 64 + cg * 8];
        const float4 w1 = *(const float4*)&Ws[k * 64 + cg * 8 + 4];
        acc[0] = fmaf(xv, w0.x, acc[0]);
        acc[1] = fmaf(xv, w0.y, acc[1]);
        acc[2] = fmaf(xv, w0.z, acc[2]);
        acc[3] = fmaf(xv, w0.w, acc[3]);
        acc[4] = fmaf(xv, w1.x, acc[4]);
        acc[5] = fmaf(xv, w1.y, acc[5]);
        acc[6] = fmaf(xv, w1.z, acc[6]);
        acc[7] = fmaf(xv, w1.w, acc[7]);
    }

    float* out = H + (size_t)(n0 + nl) * 64 + cg * 8;
    float4 o0 = make_float4(acc[0], acc[1], acc[2], acc[3]);
    float4 o1 = make_float4(acc[4], acc[5], acc[6], acc[7]);
    *(float4*)out = o0;
    *(float4*)(out + 4) = o1;
}

// ---------------- edge scatter: out[dst] += h[src]*norm ----------------
// 16 threads per edge, each handles a float4 chunk of the 64-wide feature row.

__global__ __launch_bounds__(256) void k_scatter(const float* __restrict__ H,
                                                 const float* __restrict__ norm,
                                                 const int* __restrict__ src,
                                                 const int* __restrict__ dst,
                                                 float* __restrict__ out, int e) {
    const long long gid = (long long)blockIdx.x * blockDim.x + threadIdx.x;
    const int ei = (int)(gid >> 4);
    const int c = (int)(gid & 15);
    if (ei < e) {
        const int s = src[ei];
        const int d = dst[ei];
        const float nm = norm[ei];
        const float4 hv = *(const float4*)&H[(size_t)s * 64 + c * 4];
        float* o = &out[(size_t)d * 64 + c * 4];
        atomicAdd(o + 0, hv.x * nm);
        atomicAdd(o + 1, hv.y * nm);
        atomicAdd(o + 2, hv.z * nm);
        atomicAdd(o + 3, hv.w * nm);
    }
}

// ---------------- epilogue: out = relu(out + selfnorm*h + b) ----------------

__global__ void k_epilogue(float* __restrict__ out, const float* __restrict__ H,
                           const float* __restrict__ selfnorm,
                           const float* __restrict__ b, int n) {
    const int gid = blockIdx.x * blockDim.x + threadIdx.x;
    if (gid < n * 64) {
        const int i = gid >> 6;
        const int j = gid & 63;
        float v = out[gid] + selfnorm[i] * H[gid] + b[j];
        out[gid] = v > 0.f ? v : 0.f;
    }
}

// ---------------- pooling: per-graph mean of (x1+x2+x3)/3 ----------------

__device__ __forceinline__ int lower_bound_i(const int* __restrict__ a, int n, int v) {
    int lo = 0, hi = n;
    while (lo < hi) {
        int mid = (lo + hi) >> 1;
        if (a[mid] < v) lo = mid + 1; else hi = mid;
    }
    return lo;
}

__global__ __launch_bounds__(256) void k_pool(const float* __restrict__ x1,
                                              const float* __restrict__ x2,
                                              const float* __restrict__ x3,
                                              const int* __restrict__ batch,
                                              float* __restrict__ pooled, int n) {
    const int g = blockIdx.x;
    const int tid = threadIdx.x;
    const int start = lower_bound_i(batch, n, g);
    const int end = lower_bound_i(batch, n, g + 1);

    const int j = tid & 63;
    const int q = tid >> 6;  // 0..3
    float s = 0.f;
    for (int nn = start + q; nn < end; nn += 4) {
        const size_t base = (size_t)nn * 64 + j;
        s += x1[base] + x2[base] + x3[base];
    }
    __shared__ float red[4][64];
    red[q][j] = s;
    __syncthreads();
    if (tid < 64) {
        const float t = red[0][j] + red[1][j] + red[2][j] + red[3][j];
        const int cnt = end - start;
        const float div = 3.0f * (float)(cnt < 1 ? 1 : cnt);
        pooled[g * 64 + j] = t / div;
    }
}

// ---------------- head: logits = pooled @ Wl + bl ; softmax ----------------

__global__ __launch_bounds__(256) void k_head(const float* __restrict__ pooled,
                                              const float* __restrict__ Wl,
                                              const float* __restrict__ bl,
                                              float* __restrict__ out) {
    __shared__ float Wls[64 * 10];
    __shared__ float bls[10];
    const int tid = threadIdx.x;
    for (int i = tid; i < 640; i += 256) Wls[i] = Wl[i];
    if (tid < 10) bls[tid] = bl[tid];
    __syncthreads();

    const int g = tid;  // one thread per graph, 256 threads
    float p[10];
#pragma unroll
    for (int j = 0; j < 10; ++j) p[j] = bls[j];
    for (int k = 0; k < 64; ++k) {
        const float pv = pooled[g * 64 + k];
#pragma unroll
        for (int j = 0; j < 10; ++j) p[j] = fmaf(pv, Wls[k * 10 + j], p[j]);
    }
    float m = p[0];
#pragma unroll
    for (int j = 1; j < 10; ++j) m = fmaxf(m, p[j]);
    float sum = 0.f;
#pragma unroll
    for (int j = 0; j < 10; ++j) { p[j] = expf(p[j] - m); sum += p[j]; }
    const float inv = 1.f / sum;
#pragma unroll
    for (int j = 0; j < 10; ++j) out[g * 10 + j] = p[j] * inv;
}

// ---------------- launcher ----------------

extern "C" void kernel_launch(void* const* d_in, const int* in_sizes, int n_in,
                              void* d_out, int out_size, void* d_ws, size_t ws_size,
                              hipStream_t stream) {
    const float* x  = (const float*)d_in[0];
    const float* ew = (const float*)d_in[1];
    const float* W1 = (const float*)d_in[2];
    const float* b1 = (const float*)d_in[3];
    const float* W2 = (const float*)d_in[4];
    const float* b2 = (const float*)d_in[5];
    const float* W3 = (const float*)d_in[6];
    const float* b3 = (const float*)d_in[7];
    const float* Wl = (const float*)d_in[8];
    const float* bl = (const float*)d_in[9];
    const int* eidx  = (const int*)d_in[10];
    const int* batch = (const int*)d_in[11];
    const int* src = eidx;
    const int* dst = eidx + N_EDGES;

    float* ws = (float*)d_ws;
    float* deg      = ws;                             // N
    float* selfnorm = deg + N_NODES;                  // N
    float* norm     = selfnorm + N_NODES;             // E
    float* h        = norm + N_EDGES;                 // 64N
    float* x1       = h  + (size_t)64 * N_NODES;      // 64N
    float* x2       = x1 + (size_t)64 * N_NODES;      // 64N
    float* x3       = x2 + (size_t)64 * N_NODES;      // 64N
    float* pooled   = x3 + (size_t)64 * N_NODES;      // 256*64

    float* outf = (float*)d_out;

    // zero the three scatter accumulators (x1,x2,x3 are contiguous)
    hipMemsetAsync(x1, 0, (size_t)3 * 64 * N_NODES * sizeof(float), stream);

    k_fill_deg<<<(N_NODES + 255) / 256, 256, 0, stream>>>(deg, N_NODES);
    k_deg<<<(N_EDGES + 255) / 256, 256, 0, stream>>>(ew, dst, deg, N_EDGES);
    k_dinv<<<(N_NODES + 255) / 256, 256, 0, stream>>>(deg, selfnorm, N_NODES);
    k_norm<<<(N_EDGES + 255) / 256, 256, 0, stream>>>(ew, src, dst, deg, norm, N_EDGES);

    // layer 1
    k_gemm<128><<<N_NODES / 32, 256, 0, stream>>>(x, W1, h, N_NODES);
    k_scatter<<<(N_EDGES * 16) / 256, 256, 0, stream>>>(h, norm, src, dst, x1, N_EDGES);
    k_epilogue<<<(N_NODES * 64) / 256, 256, 0, stream>>>(x1, h, selfnorm, b1, N_NODES);
    // layer 2
    k_gemm<64><<<N_NODES / 32, 256, 0, stream>>>(x1, W2, h, N_NODES);
    k_scatter<<<(N_EDGES * 16) / 256, 256, 0, stream>>>(h, norm, src, dst, x2, N_EDGES);
    k_epilogue<<<(N_NODES * 64) / 256, 256, 0, stream>>>(x2, h, selfnorm, b2, N_NODES);
    // layer 3
    k_gemm<64><<<N_NODES / 32, 256, 0, stream>>>(x2, W3, h, N_NODES);
    k_scatter<<<(N_EDGES * 16) / 256, 256, 0, stream>>>(h, norm, src, dst, x3, N_EDGES);
    k_epilogue<<<(N_NODES * 64) / 256, 256, 0, stream>>>(x3, h, selfnorm, b3, N_NODES);

    // readout
    k_pool<<<N_GRAPHS, 256, 0, stream>>>(x1, x2, x3, batch, pooled, N_NODES);
    k_head<<<1, 256, 0, stream>>>(pooled, Wl, bl, outf);
}

// Round 2
// 749.389 us; speedup vs baseline: 5.7891x; 5.7891x over previous
//
#include <hip/hip_runtime.h>
#include <hip/hip_bf16.h>
#include <math.h>

#define N_NODES 100000
#define N_EDGES 1600000
#define N_GRAPHS 256
#define IN_DIM 128
#define F_SIZE 64
#define OUT_DIM 10

// ---------------- degree (weighted) + in-degree count ----------------

__global__ void k_fill_deg(float* __restrict__ deg, int n) {
    int i = blockIdx.x * blockDim.x + threadIdx.x;
    if (i < n) deg[i] = 1.0f;  // self-loop weight
}

__global__ void k_deg(const float* __restrict__ ew, const int* __restrict__ dst,
                      float* __restrict__ deg, int* __restrict__ cnt, int e) {
    int i = blockIdx.x * blockDim.x + threadIdx.x;
    if (i < e) {
        int d = dst[i];
        atomicAdd(&deg[d], fabsf(ew[i]));
        atomicAdd(&cnt[d], 1);
    }
}

__global__ void k_dinv(float* __restrict__ deg, float* __restrict__ selfnorm, int n) {
    int i = blockIdx.x * blockDim.x + threadIdx.x;
    if (i < n) {
        float d = deg[i];
        float di = (d > 0.f) ? (1.0f / sqrtf(d)) : 0.f;
        deg[i] = di;          // deg now holds dinv
        selfnorm[i] = di * di;
    }
}

// ---------------- prefix scan (1024 elems / block) ----------------

__global__ __launch_bounds__(256) void k_scan_local(const int* __restrict__ in,
                                                    int* __restrict__ outloc,
                                                    int* __restrict__ bsum, int n) {
    __shared__ int ts[256];
    const int tid = threadIdx.x;
    const int base = blockIdx.x * 1024 + tid * 4;
    int v0 = 0, v1 = 0, v2 = 0, v3 = 0;
    if (base + 3 < n) {
        v0 = in[base]; v1 = in[base + 1]; v2 = in[base + 2]; v3 = in[base + 3];
    } else {
        if (base + 0 < n) v0 = in[base];
        if (base + 1 < n) v1 = in[base + 1];
        if (base + 2 < n) v2 = in[base + 2];
    }
    const int s = v0 + v1 + v2 + v3;
    ts[tid] = s;
    __syncthreads();
    for (int off = 1; off < 256; off <<= 1) {
        int y = (tid >= off) ? ts[tid - off] : 0;
        __syncthreads();
        ts[tid] += y;
        __syncthreads();
    }
    const int incl = ts[tid];
    if (tid == 255) bsum[blockIdx.x] = incl;
    int run = incl - s;  // exclusive
    if (base < n)     outloc[base]     = run;
    run += v0;
    if (base + 1 < n) outloc[base + 1] = run;
    run += v1;
    if (base + 2 < n) outloc[base + 2] = run;
    run += v2;
    if (base + 3 < n) outloc[base + 3] = run;
}

__global__ void k_scan_bsum(int* __restrict__ bsum, int nb) {
    if (threadIdx.x == 0 && blockIdx.x == 0) {
        int acc = 0;
        for (int i = 0; i < nb; ++i) { int t = bsum[i]; bsum[i] = acc; acc += t; }
    }
}

__global__ void k_scan_finish(int* __restrict__ rowptr, const int* __restrict__ bsum,
                              int* __restrict__ wpos, int n, int e) {
    int i = blockIdx.x * blockDim.x + threadIdx.x;
    if (i < n) {
        int v = rowptr[i] + bsum[i >> 10];
        rowptr[i] = v;
        wpos[i] = v;
    }
    if (i == 0) rowptr[n] = e;
}

// ---------------- CSR fill (dst-sorted; norm computed inline) ----------------

__global__ void k_csr_fill(const int* __restrict__ src, const int* __restrict__ dst,
                           const float* __restrict__ ew, const float* __restrict__ dinv,
                           int* __restrict__ wpos, int* __restrict__ csr_src,
                           float* __restrict__ csr_norm, int e) {
    int i = blockIdx.x * blockDim.x + threadIdx.x;
    if (i < e) {
        const int s = src[i];
        const int d = dst[i];
        const float nm = dinv[s] * fabsf(ew[i]) * dinv[d];
        const int pos = atomicAdd(&wpos[d], 1);
        csr_src[pos] = s;
        csr_norm[pos] = nm;
    }
}

// ---------------- GEMM: H[n][64] = X[n][K] @ W[K][64] ----------------

template <int K>
__global__ __launch_bounds__(256) void k_gemm(const float* __restrict__ X,
                                              const float* __restrict__ W,
                                              float* __restrict__ H, int n) {
    __shared__ __align__(16) float Ws[K * 64];
    __shared__ float Xs[32 * (K + 2)];
    const int tid = threadIdx.x;
    const int n0 = blockIdx.x * 32;

    for (int i = tid; i < K * 16; i += 256) {
        ((float4*)Ws)[i] = ((const float4*)W)[i];
    }
    for (int i = tid; i < 32 * (K / 4); i += 256) {
        const int r = i / (K / 4);
        const int c = i % (K / 4);
        const float4 v = ((const float4*)(X + (size_t)(n0 + r) * K))[c];
        float* p = &Xs[r * (K + 2) + c * 4];
        p[0] = v.x; p[1] = v.y; p[2] = v.z; p[3] = v.w;
    }
    __syncthreads();

    const int nl = tid >> 3;
    const int cg = tid & 7;
    float acc[8];
#pragma unroll
    for (int j = 0; j < 8; ++j) acc[j] = 0.f;

#pragma unroll 4
    for (int k = 0; k < K; ++k) {
        const float xv = Xs[nl * (K + 2) + k];
        const float4 w0 = *(const float4*)&Ws[k * 64 + cg * 8];
        const float4 w1 = *(const float4*)&Ws[k * 64 + cg * 8 + 4];
        acc[0] = fmaf(xv, w0.x, acc[0]);
        acc[1] = fmaf(xv, w0.y, acc[1]);
        acc[2] = fmaf(xv, w0.z, acc[2]);
        acc[3] = fmaf(xv, w0.w, acc[3]);
        acc[4] = fmaf(xv, w1.x, acc[4]);
        acc[5] = fmaf(xv, w1.y, acc[5]);
        acc[6] = fmaf(xv, w1.z, acc[6]);
        acc[7] = fmaf(xv, w1.w, acc[7]);
    }

    float* out = H + (size_t)(n0 + nl) * 64 + cg * 8;
    *(float4*)out = make_float4(acc[0], acc[1], acc[2], acc[3]);
    *(float4*)(out + 4) = make_float4(acc[4], acc[5], acc[6], acc[7]);
}

// ------- aggregate (gather): out = relu(sum_in norm*H[src] + selfnorm*H + b) -------
// 1 wave (64 lanes) per dst node, lane = feature; 4 nodes per 256-thread block.

__global__ __launch_bounds__(256) void k_agg(const float* __restrict__ H,
                                             const int* __restrict__ rowptr,
                                             const int* __restrict__ csr_src,
                                             const float* __restrict__ csr_norm,
                                             const float* __restrict__ selfnorm,
                                             const float* __restrict__ b,
                                             float* __restrict__ out, int n) {
    const int node = blockIdx.x * 4 + (threadIdx.x >> 6);
    const int j = threadIdx.x & 63;
    if (node >= n) return;
    const int p0 = rowptr[node];
    const int p1 = rowptr[node + 1];
    float acc = fmaf(selfnorm[node], H[(size_t)node * 64 + j], b[j]);
    int p = p0;
    for (; p + 3 < p1; p += 4) {
        const int s0 = csr_src[p], s1 = csr_src[p + 1];
        const int s2 = csr_src[p + 2], s3 = csr_src[p + 3];
        const float n0 = csr_norm[p], n1 = csr_norm[p + 1];
        const float n2 = csr_norm[p + 2], n3 = csr_norm[p + 3];
        const float h0 = H[(size_t)s0 * 64 + j];
        const float h1 = H[(size_t)s1 * 64 + j];
        const float h2 = H[(size_t)s2 * 64 + j];
        const float h3 = H[(size_t)s3 * 64 + j];
        acc = fmaf(n0, h0, acc);
        acc = fmaf(n1, h1, acc);
        acc = fmaf(n2, h2, acc);
        acc = fmaf(n3, h3, acc);
    }
    for (; p < p1; ++p) {
        acc = fmaf(csr_norm[p], H[(size_t)csr_src[p] * 64 + j], acc);
    }
    out[(size_t)node * 64 + j] = fmaxf(acc, 0.f);
}

// ---------------- pooling: accumulate per-graph sums ----------------

__device__ __forceinline__ int lower_bound_i(const int* __restrict__ a, int n, int v) {
    int lo = 0, hi = n;
    while (lo < hi) {
        int mid = (lo + hi) >> 1;
        if (a[mid] < v) lo = mid + 1; else hi = mid;
    }
    return lo;
}

__global__ __launch_bounds__(256) void k_pool_add(const float* __restrict__ xl,
                                                  const int* __restrict__ batch,
                                                  float* __restrict__ pooled, int n) {
    const int g = blockIdx.x;
    const int tid = threadIdx.x;
    const int start = lower_bound_i(batch, n, g);
    const int end = lower_bound_i(batch, n, g + 1);

    const int j = tid & 63;
    const int q = tid >> 6;  // 0..3
    float s = 0.f;
    for (int nn = start + q; nn < end; nn += 4) {
        s += xl[(size_t)nn * 64 + j];
    }
    __shared__ float red[4][64];
    red[q][j] = s;
    __syncthreads();
    if (tid < 64) {
        pooled[g * 64 + j] += red[0][j] + red[1][j] + red[2][j] + red[3][j];
    }
}

// ---------------- head: logits = pooled/(3*cnt) @ Wl + bl ; softmax ----------------

__global__ __launch_bounds__(256) void k_head(const float* __restrict__ pooled,
                                              const int* __restrict__ batch,
                                              const float* __restrict__ Wl,
                                              const float* __restrict__ bl,
                                              float* __restrict__ out, int n) {
    __shared__ float Wls[64 * 10];
    __shared__ float bls[10];
    const int tid = threadIdx.x;
    for (int i = tid; i < 640; i += 256) Wls[i] = Wl[i];
    if (tid < 10) bls[tid] = bl[tid];
    __syncthreads();

    const int g = tid;  // one thread per graph
    const int start = lower_bound_i(batch, n, g);
    const int end = lower_bound_i(batch, n, g + 1);
    const int cnt = end - start;
    const float scale = 1.0f / (3.0f * (float)(cnt < 1 ? 1 : cnt));

    float p[10];
#pragma unroll
    for (int j = 0; j < 10; ++j) p[j] = bls[j];
    for (int k = 0; k < 64; ++k) {
        const float pv = pooled[g * 64 + k] * scale;
#pragma unroll
        for (int j = 0; j < 10; ++j) p[j] = fmaf(pv, Wls[k * 10 + j], p[j]);
    }
    float m = p[0];
#pragma unroll
    for (int j = 1; j < 10; ++j) m = fmaxf(m, p[j]);
    float sum = 0.f;
#pragma unroll
    for (int j = 0; j < 10; ++j) { p[j] = expf(p[j] - m); sum += p[j]; }
    const float inv = 1.f / sum;
#pragma unroll
    for (int j = 0; j < 10; ++j) out[g * 10 + j] = p[j] * inv;
}

// ---------------- launcher ----------------

extern "C" void kernel_launch(void* const* d_in, const int* in_sizes, int n_in,
                              void* d_out, int out_size, void* d_ws, size_t ws_size,
                              hipStream_t stream) {
    const float* x  = (const float*)d_in[0];
    const float* ew = (const float*)d_in[1];
    const float* W1 = (const float*)d_in[2];
    const float* b1 = (const float*)d_in[3];
    const float* W2 = (const float*)d_in[4];
    const float* b2 = (const float*)d_in[5];
    const float* W3 = (const float*)d_in[6];
    const float* b3 = (const float*)d_in[7];
    const float* Wl = (const float*)d_in[8];
    const float* bl = (const float*)d_in[9];
    const int* eidx  = (const int*)d_in[10];
    const int* batch = (const int*)d_in[11];
    const int* src = eidx;
    const int* dst = eidx + N_EDGES;

    // workspace layout (all element-counts multiples of 16 -> 16B aligned)
    float* ws = (float*)d_ws;
    float* deg      = ws;                               // N
    float* selfnorm = deg + N_NODES;                    // N
    int*   cnt      = (int*)(selfnorm + N_NODES);       // N (reused as wpos)
    int*   rowptr   = cnt + N_NODES;                    // N+16
    int*   bsum     = rowptr + N_NODES + 16;            // 256
    int*   csr_src  = bsum + 256;                       // E
    float* csr_norm = (float*)(csr_src + N_EDGES);      // E
    float* h        = csr_norm + N_EDGES;               // 64N
    float* A        = h + (size_t)64 * N_NODES;         // 64N
    float* B        = A + (size_t)64 * N_NODES;         // 64N
    float* pooled   = B + (size_t)64 * N_NODES;         // 256*64

    float* outf = (float*)d_out;

    hipMemsetAsync(cnt, 0, N_NODES * sizeof(int), stream);
    hipMemsetAsync(pooled, 0, N_GRAPHS * F_SIZE * sizeof(float), stream);

    k_fill_deg<<<(N_NODES + 255) / 256, 256, 0, stream>>>(deg, N_NODES);
    k_deg<<<(N_EDGES + 255) / 256, 256, 0, stream>>>(ew, dst, deg, cnt, N_EDGES);
    k_dinv<<<(N_NODES + 255) / 256, 256, 0, stream>>>(deg, selfnorm, N_NODES);

    const int nb = (N_NODES + 1023) / 1024;  // 98
    k_scan_local<<<nb, 256, 0, stream>>>(cnt, rowptr, bsum, N_NODES);
    k_scan_bsum<<<1, 64, 0, stream>>>(bsum, nb);
    k_scan_finish<<<(N_NODES + 255) / 256, 256, 0, stream>>>(rowptr, bsum, cnt, N_NODES, N_EDGES);
    k_csr_fill<<<(N_EDGES + 255) / 256, 256, 0, stream>>>(src, dst, ew, deg, cnt,
                                                          csr_src, csr_norm, N_EDGES);

    const int nagg = (N_NODES + 3) / 4;

    // layer 1
    k_gemm<128><<<N_NODES / 32, 256, 0, stream>>>(x, W1, h, N_NODES);
    k_agg<<<nagg, 256, 0, stream>>>(h, rowptr, csr_src, csr_norm, selfnorm, b1, A, N_NODES);
    k_pool_add<<<N_GRAPHS, 256, 0, stream>>>(A, batch, pooled, N_NODES);
    // layer 2
    k_gemm<64><<<N_NODES / 32, 256, 0, stream>>>(A, W2, h, N_NODES);
    k_agg<<<nagg, 256, 0, stream>>>(h, rowptr, csr_src, csr_norm, selfnorm, b2, B, N_NODES);
    k_pool_add<<<N_GRAPHS, 256, 0, stream>>>(B, batch, pooled, N_NODES);
    // layer 3
    k_gemm<64><<<N_NODES / 32, 256, 0, stream>>>(B, W3, h, N_NODES);
    k_agg<<<nagg, 256, 0, stream>>>(h, rowptr, csr_src, csr_norm, selfnorm, b3, A, N_NODES);
    k_pool_add<<<N_GRAPHS, 256, 0, stream>>>(A, batch, pooled, N_NODES);

    k_head<<<1, 256, 0, stream>>>(pooled, batch, Wl, bl, outf, N_NODES);
}

// Round 3
// 696.935 us; speedup vs baseline: 6.2248x; 1.0753x over previous
//
#include <hip/hip_runtime.h>
#include <hip/hip_bf16.h>
#include <math.h>

#define N_NODES 100000
#define N_EDGES 1600000
#define N_GRAPHS 256
#define IN_DIM 128
#define F_SIZE 64
#define OUT_DIM 10

// ---------------- in-degree count (one int atomic per edge) ----------------

__global__ void k_cnt(const int* __restrict__ dst, int* __restrict__ cnt, int e) {
    int i = blockIdx.x * blockDim.x + threadIdx.x;
    if (i < e) atomicAdd(&cnt[dst[i]], 1);
}

// ---------------- prefix scan (1024 elems / block) ----------------

__global__ __launch_bounds__(256) void k_scan_local(const int* __restrict__ in,
                                                    int* __restrict__ outloc,
                                                    int* __restrict__ bsum, int n) {
    __shared__ int ts[256];
    const int tid = threadIdx.x;
    const int base = blockIdx.x * 1024 + tid * 4;
    int v0 = 0, v1 = 0, v2 = 0, v3 = 0;
    if (base + 3 < n) {
        v0 = in[base]; v1 = in[base + 1]; v2 = in[base + 2]; v3 = in[base + 3];
    } else {
        if (base + 0 < n) v0 = in[base];
        if (base + 1 < n) v1 = in[base + 1];
        if (base + 2 < n) v2 = in[base + 2];
    }
    const int s = v0 + v1 + v2 + v3;
    ts[tid] = s;
    __syncthreads();
    for (int off = 1; off < 256; off <<= 1) {
        int y = (tid >= off) ? ts[tid - off] : 0;
        __syncthreads();
        ts[tid] += y;
        __syncthreads();
    }
    const int incl = ts[tid];
    if (tid == 255) bsum[blockIdx.x] = incl;
    int run = incl - s;  // exclusive
    if (base < n)     outloc[base]     = run;
    run += v0;
    if (base + 1 < n) outloc[base + 1] = run;
    run += v1;
    if (base + 2 < n) outloc[base + 2] = run;
    run += v2;
    if (base + 3 < n) outloc[base + 3] = run;
}

__global__ void k_scan_bsum(int* __restrict__ bsum, int nb) {
    if (threadIdx.x == 0 && blockIdx.x == 0) {
        int acc = 0;
        for (int i = 0; i < nb; ++i) { int t = bsum[i]; bsum[i] = acc; acc += t; }
    }
}

__global__ void k_scan_finish(int* __restrict__ rowptr, const int* __restrict__ bsum,
                              int* __restrict__ wpos, int n, int e) {
    int i = blockIdx.x * blockDim.x + threadIdx.x;
    if (i < n) {
        int v = rowptr[i] + bsum[i >> 10];
        rowptr[i] = v;
        wpos[i] = v;
    }
    if (i == 0) rowptr[n] = e;
}

// ------- CSR fill: interleaved int2 {src, bits(|w|)} — one 8B store per edge -------

__global__ void k_csr_fill(const int* __restrict__ src, const int* __restrict__ dst,
                           const float* __restrict__ ew, int* __restrict__ wpos,
                           int2* __restrict__ csr, int e) {
    int i = blockIdx.x * blockDim.x + threadIdx.x;
    if (i < e) {
        const int s = src[i];
        const int d = dst[i];
        const float w = fabsf(ew[i]);
        const int pos = atomicAdd(&wpos[d], 1);
        csr[pos] = make_int2(s, __float_as_int(w));
    }
}

// ------- per-node weighted degree from CSR (contiguous, no atomics) -------

__global__ void k_degsum(const int2* __restrict__ csr, const int* __restrict__ rowptr,
                         float* __restrict__ dinv, float* __restrict__ selfnorm, int n) {
    int i = blockIdx.x * blockDim.x + threadIdx.x;
    if (i < n) {
        const int p0 = rowptr[i];
        const int p1 = rowptr[i + 1];
        float s = 1.0f;  // self-loop weight
        for (int p = p0; p < p1; ++p) s += __int_as_float(csr[p].y);
        const float di = (s > 0.f) ? (1.0f / sqrtf(s)) : 0.f;
        dinv[i] = di;
        selfnorm[i] = di * di;
    }
}

// ------- in-place |w| -> norm = dinv[src]*|w|*dinv[dst] -------

__global__ void k_normcsr(int2* __restrict__ csr, const int* __restrict__ rowptr,
                          const float* __restrict__ dinv, int n) {
    int i = blockIdx.x * blockDim.x + threadIdx.x;
    if (i < n) {
        const float dn = dinv[i];
        const int p1 = rowptr[i + 1];
        for (int p = rowptr[i]; p < p1; ++p) {
            int2 c = csr[p];
            const float nm = __int_as_float(c.y) * dn * dinv[c.x];
            csr[p].y = __float_as_int(nm);
        }
    }
}

// ---------------- GEMM: H[n][64] = X[n][K] @ W[K][64] ----------------

template <int K>
__global__ __launch_bounds__(256) void k_gemm(const float* __restrict__ X,
                                              const float* __restrict__ W,
                                              float* __restrict__ H, int n) {
    __shared__ __align__(16) float Ws[K * 64];
    __shared__ float Xs[32 * (K + 2)];
    const int tid = threadIdx.x;
    const int n0 = blockIdx.x * 32;

    for (int i = tid; i < K * 16; i += 256) {
        ((float4*)Ws)[i] = ((const float4*)W)[i];
    }
    for (int i = tid; i < 32 * (K / 4); i += 256) {
        const int r = i / (K / 4);
        const int c = i % (K / 4);
        const float4 v = ((const float4*)(X + (size_t)(n0 + r) * K))[c];
        float* p = &Xs[r * (K + 2) + c * 4];
        p[0] = v.x; p[1] = v.y; p[2] = v.z; p[3] = v.w;
    }
    __syncthreads();

    const int nl = tid >> 3;
    const int cg = tid & 7;
    float acc[8];
#pragma unroll
    for (int j = 0; j < 8; ++j) acc[j] = 0.f;

#pragma unroll 4
    for (int k = 0; k < K; ++k) {
        const float xv = Xs[nl * (K + 2) + k];
        const float4 w0 = *(const float4*)&Ws[k * 64 + cg * 8];
        const float4 w1 = *(const float4*)&Ws[k * 64 + cg * 8 + 4];
        acc[0] = fmaf(xv, w0.x, acc[0]);
        acc[1] = fmaf(xv, w0.y, acc[1]);
        acc[2] = fmaf(xv, w0.z, acc[2]);
        acc[3] = fmaf(xv, w0.w, acc[3]);
        acc[4] = fmaf(xv, w1.x, acc[4]);
        acc[5] = fmaf(xv, w1.y, acc[5]);
        acc[6] = fmaf(xv, w1.z, acc[6]);
        acc[7] = fmaf(xv, w1.w, acc[7]);
    }

    float* out = H + (size_t)(n0 + nl) * 64 + cg * 8;
    *(float4*)out = make_float4(acc[0], acc[1], acc[2], acc[3]);
    *(float4*)(out + 4) = make_float4(acc[4], acc[5], acc[6], acc[7]);
}

// ------- aggregate (gather): out = relu(sum_in norm*H[src] + selfnorm*H + b) -------
// 1 wave (64 lanes) per dst node, lane = feature; 4 nodes per 256-thread block.

__global__ __launch_bounds__(256) void k_agg(const float* __restrict__ H,
                                             const int* __restrict__ rowptr,
                                             const int2* __restrict__ csr,
                                             const float* __restrict__ selfnorm,
                                             const float* __restrict__ b,
                                             float* __restrict__ out, int n) {
    const int node = blockIdx.x * 4 + (threadIdx.x >> 6);
    const int j = threadIdx.x & 63;
    if (node >= n) return;
    const int p0 = rowptr[node];
    const int p1 = rowptr[node + 1];
    float acc = fmaf(selfnorm[node], H[(size_t)node * 64 + j], b[j]);
    int p = p0;
    for (; p + 3 < p1; p += 4) {
        const int2 c0 = csr[p];
        const int2 c1 = csr[p + 1];
        const int2 c2 = csr[p + 2];
        const int2 c3 = csr[p + 3];
        const float h0 = H[(size_t)c0.x * 64 + j];
        const float h1 = H[(size_t)c1.x * 64 + j];
        const float h2 = H[(size_t)c2.x * 64 + j];
        const float h3 = H[(size_t)c3.x * 64 + j];
        acc = fmaf(__int_as_float(c0.y), h0, acc);
        acc = fmaf(__int_as_float(c1.y), h1, acc);
        acc = fmaf(__int_as_float(c2.y), h2, acc);
        acc = fmaf(__int_as_float(c3.y), h3, acc);
    }
    for (; p < p1; ++p) {
        const int2 c = csr[p];
        acc = fmaf(__int_as_float(c.y), H[(size_t)c.x * 64 + j], acc);
    }
    out[(size_t)node * 64 + j] = fmaxf(acc, 0.f);
}

// ---------------- pooling: accumulate per-graph sums ----------------

__device__ __forceinline__ int lower_bound_i(const int* __restrict__ a, int n, int v) {
    int lo = 0, hi = n;
    while (lo < hi) {
        int mid = (lo + hi) >> 1;
        if (a[mid] < v) lo = mid + 1; else hi = mid;
    }
    return lo;
}

__global__ __launch_bounds__(256) void k_pool_add(const float* __restrict__ xl,
                                                  const int* __restrict__ batch,
                                                  float* __restrict__ pooled, int n) {
    const int g = blockIdx.x;
    const int tid = threadIdx.x;
    const int start = lower_bound_i(batch, n, g);
    const int end = lower_bound_i(batch, n, g + 1);

    const int j = tid & 63;
    const int q = tid >> 6;  // 0..3
    float s = 0.f;
    for (int nn = start + q; nn < end; nn += 4) {
        s += xl[(size_t)nn * 64 + j];
    }
    __shared__ float red[4][64];
    red[q][j] = s;
    __syncthreads();
    if (tid < 64) {
        pooled[g * 64 + j] += red[0][j] + red[1][j] + red[2][j] + red[3][j];
    }
}

// ---------------- head: logits = pooled/(3*cnt) @ Wl + bl ; softmax ----------------

__global__ __launch_bounds__(256) void k_head(const float* __restrict__ pooled,
                                              const int* __restrict__ batch,
                                              const float* __restrict__ Wl,
                                              const float* __restrict__ bl,
                                              float* __restrict__ out, int n) {
    __shared__ float Wls[64 * 10];
    __shared__ float bls[10];
    const int tid = threadIdx.x;
    for (int i = tid; i < 640; i += 256) Wls[i] = Wl[i];
    if (tid < 10) bls[tid] = bl[tid];
    __syncthreads();

    const int g = tid;  // one thread per graph
    const int start = lower_bound_i(batch, n, g);
    const int end = lower_bound_i(batch, n, g + 1);
    const int cnt = end - start;
    const float scale = 1.0f / (3.0f * (float)(cnt < 1 ? 1 : cnt));

    float p[10];
#pragma unroll
    for (int j = 0; j < 10; ++j) p[j] = bls[j];
    for (int k = 0; k < 64; ++k) {
        const float pv = pooled[g * 64 + k] * scale;
#pragma unroll
        for (int j = 0; j < 10; ++j) p[j] = fmaf(pv, Wls[k * 10 + j], p[j]);
    }
    float m = p[0];
#pragma unroll
    for (int j = 1; j < 10; ++j) m = fmaxf(m, p[j]);
    float sum = 0.f;
#pragma unroll
    for (int j = 0; j < 10; ++j) { p[j] = expf(p[j] - m); sum += p[j]; }
    const float inv = 1.f / sum;
#pragma unroll
    for (int j = 0; j < 10; ++j) out[g * 10 + j] = p[j] * inv;
}

// ---------------- launcher ----------------

extern "C" void kernel_launch(void* const* d_in, const int* in_sizes, int n_in,
                              void* d_out, int out_size, void* d_ws, size_t ws_size,
                              hipStream_t stream) {
    const float* x  = (const float*)d_in[0];
    const float* ew = (const float*)d_in[1];
    const float* W1 = (const float*)d_in[2];
    const float* b1 = (const float*)d_in[3];
    const float* W2 = (const float*)d_in[4];
    const float* b2 = (const float*)d_in[5];
    const float* W3 = (const float*)d_in[6];
    const float* b3 = (const float*)d_in[7];
    const float* Wl = (const float*)d_in[8];
    const float* bl = (const float*)d_in[9];
    const int* eidx  = (const int*)d_in[10];
    const int* batch = (const int*)d_in[11];
    const int* src = eidx;
    const int* dst = eidx + N_EDGES;

    // workspace layout (all region sizes multiples of 16 elements -> 16B aligned)
    float* ws = (float*)d_ws;
    float* dinv     = ws;                               // N
    float* selfnorm = dinv + N_NODES;                   // N
    int*   cnt      = (int*)(selfnorm + N_NODES);       // N (reused as wpos)
    int*   rowptr   = cnt + N_NODES;                    // N+16
    int*   bsum     = rowptr + N_NODES + 16;            // 256
    int2*  csr      = (int2*)(bsum + 256);              // E (int2 = 8B)
    float* h        = (float*)(csr + N_EDGES);          // 64N
    float* A        = h + (size_t)64 * N_NODES;         // 64N
    float* B        = A + (size_t)64 * N_NODES;         // 64N
    float* pooled   = B + (size_t)64 * N_NODES;         // 256*64

    float* outf = (float*)d_out;

    hipMemsetAsync(cnt, 0, N_NODES * sizeof(int), stream);
    hipMemsetAsync(pooled, 0, N_GRAPHS * F_SIZE * sizeof(float), stream);

    // ---- CSR build ----
    k_cnt<<<(N_EDGES + 255) / 256, 256, 0, stream>>>(dst, cnt, N_EDGES);
    const int nb = (N_NODES + 1023) / 1024;  // 98
    k_scan_local<<<nb, 256, 0, stream>>>(cnt, rowptr, bsum, N_NODES);
    k_scan_bsum<<<1, 64, 0, stream>>>(bsum, nb);
    k_scan_finish<<<(N_NODES + 255) / 256, 256, 0, stream>>>(rowptr, bsum, cnt, N_NODES, N_EDGES);
    k_csr_fill<<<(N_EDGES + 255) / 256, 256, 0, stream>>>(src, dst, ew, cnt, csr, N_EDGES);
    k_degsum<<<(N_NODES + 255) / 256, 256, 0, stream>>>(csr, rowptr, dinv, selfnorm, N_NODES);
    k_normcsr<<<(N_NODES + 255) / 256, 256, 0, stream>>>(csr, rowptr, dinv, N_NODES);

    const int nagg = (N_NODES + 3) / 4;

    // layer 1
    k_gemm<128><<<N_NODES / 32, 256, 0, stream>>>(x, W1, h, N_NODES);
    k_agg<<<nagg, 256, 0, stream>>>(h, rowptr, csr, selfnorm, b1, A, N_NODES);
    k_pool_add<<<N_GRAPHS, 256, 0, stream>>>(A, batch, pooled, N_NODES);
    // layer 2
    k_gemm<64><<<N_NODES / 32, 256, 0, stream>>>(A, W2, h, N_NODES);
    k_agg<<<nagg, 256, 0, stream>>>(h, rowptr, csr, selfnorm, b2, B, N_NODES);
    k_pool_add<<<N_GRAPHS, 256, 0, stream>>>(B, batch, pooled, N_NODES);
    // layer 3
    k_gemm<64><<<N_NODES / 32, 256, 0, stream>>>(B, W3, h, N_NODES);
    k_agg<<<nagg, 256, 0, stream>>>(h, rowptr, csr, selfnorm, b3, A, N_NODES);
    k_pool_add<<<N_GRAPHS, 256, 0, stream>>>(A, batch, pooled, N_NODES);

    k_head<<<1, 256, 0, stream>>>(pooled, batch, Wl, bl, outf, N_NODES);
}

// Round 4
// 542.698 us; speedup vs baseline: 7.9939x; 1.2842x over previous
//
#include <hip/hip_runtime.h>
#include <hip/hip_fp16.h>
#include <math.h>

#define N_NODES 100000
#define N_EDGES 1600000
#define N_GRAPHS 256
#define IN_DIM 128
#define F_SIZE 64
#define OUT_DIM 10

// ------- pass 1: in-degree count + rank-within-row (one int atomic per edge) -------

__global__ void k_cnt_pos(const int* __restrict__ dst, int* __restrict__ cnt,
                          int* __restrict__ pos, int e) {
    int i = blockIdx.x * blockDim.x + threadIdx.x;
    if (i < e) pos[i] = atomicAdd(&cnt[dst[i]], 1);
}

// ---------------- prefix scan (1024 elems / block) ----------------

__global__ __launch_bounds__(256) void k_scan_local(const int* __restrict__ in,
                                                    int* __restrict__ outloc,
                                                    int* __restrict__ bsum, int n) {
    __shared__ int ts[256];
    const int tid = threadIdx.x;
    const int base = blockIdx.x * 1024 + tid * 4;
    int v0 = 0, v1 = 0, v2 = 0, v3 = 0;
    if (base + 3 < n) {
        v0 = in[base]; v1 = in[base + 1]; v2 = in[base + 2]; v3 = in[base + 3];
    } else {
        if (base + 0 < n) v0 = in[base];
        if (base + 1 < n) v1 = in[base + 1];
        if (base + 2 < n) v2 = in[base + 2];
    }
    const int s = v0 + v1 + v2 + v3;
    ts[tid] = s;
    __syncthreads();
    for (int off = 1; off < 256; off <<= 1) {
        int y = (tid >= off) ? ts[tid - off] : 0;
        __syncthreads();
        ts[tid] += y;
        __syncthreads();
    }
    const int incl = ts[tid];
    if (tid == 255) bsum[blockIdx.x] = incl;
    int run = incl - s;  // exclusive
    if (base < n)     outloc[base]     = run;
    run += v0;
    if (base + 1 < n) outloc[base + 1] = run;
    run += v1;
    if (base + 2 < n) outloc[base + 2] = run;
    run += v2;
    if (base + 3 < n) outloc[base + 3] = run;
}

__global__ void k_scan_bsum(int* __restrict__ bsum, int nb) {
    if (threadIdx.x == 0 && blockIdx.x == 0) {
        int acc = 0;
        for (int i = 0; i < nb; ++i) { int t = bsum[i]; bsum[i] = acc; acc += t; }
    }
}

__global__ void k_scan_finish(int* __restrict__ rowptr, const int* __restrict__ bsum,
                              int n, int e) {
    int i = blockIdx.x * blockDim.x + threadIdx.x;
    if (i < n) rowptr[i] += bsum[i >> 10];
    if (i == 0) rowptr[n] = e;
}

// ------- pass 2: CSR fill, atomic-free: csr[rowptr[d]+pos[i]] = {src, |w|} -------

__global__ void k_csr_fill(const int* __restrict__ src, const int* __restrict__ dst,
                           const float* __restrict__ ew, const int* __restrict__ rowptr,
                           const int* __restrict__ pos, int2* __restrict__ csr, int e) {
    int i = blockIdx.x * blockDim.x + threadIdx.x;
    if (i < e) {
        const int d = dst[i];
        const int p = rowptr[d] + pos[i];
        csr[p] = make_int2(src[i], __float_as_int(fabsf(ew[i])));
    }
}

// ------- per-node weighted degree from CSR -> dinv (contiguous, no atomics) -------

__global__ void k_degsum(const int2* __restrict__ csr, const int* __restrict__ rowptr,
                         float* __restrict__ dinv, int n) {
    int i = blockIdx.x * blockDim.x + threadIdx.x;
    if (i < n) {
        const int p0 = rowptr[i];
        const int p1 = rowptr[i + 1];
        float s = 1.0f;  // self-loop weight
        for (int p = p0; p < p1; ++p) s += __int_as_float(csr[p].y);
        dinv[i] = (s > 0.f) ? (1.0f / sqrtf(s)) : 0.f;
    }
}

// ------- GEMM: Hs[n][64] = fp16( dinv[n] * (X[n][K] @ W[K][64]) ) -------

template <int K>
__global__ __launch_bounds__(256) void k_gemm(const float* __restrict__ X,
                                              const float* __restrict__ W,
                                              const float* __restrict__ dinv,
                                              __half* __restrict__ Hs, int n) {
    __shared__ __align__(16) float Ws[K * 64];
    __shared__ float Xs[32 * (K + 2)];
    const int tid = threadIdx.x;
    const int n0 = blockIdx.x * 32;

    for (int i = tid; i < K * 16; i += 256) {
        ((float4*)Ws)[i] = ((const float4*)W)[i];
    }
    for (int i = tid; i < 32 * (K / 4); i += 256) {
        const int r = i / (K / 4);
        const int c = i % (K / 4);
        const float4 v = ((const float4*)(X + (size_t)(n0 + r) * K))[c];
        float* p = &Xs[r * (K + 2) + c * 4];
        p[0] = v.x; p[1] = v.y; p[2] = v.z; p[3] = v.w;
    }
    __syncthreads();

    const int nl = tid >> 3;
    const int cg = tid & 7;
    float acc[8];
#pragma unroll
    for (int j = 0; j < 8; ++j) acc[j] = 0.f;

#pragma unroll 4
    for (int k = 0; k < K; ++k) {
        const float xv = Xs[nl * (K + 2) + k];
        const float4 w0 = *(const float4*)&Ws[k * 64 + cg * 8];
        const float4 w1 = *(const float4*)&Ws[k * 64 + cg * 8 + 4];
        acc[0] = fmaf(xv, w0.x, acc[0]);
        acc[1] = fmaf(xv, w0.y, acc[1]);
        acc[2] = fmaf(xv, w0.z, acc[2]);
        acc[3] = fmaf(xv, w0.w, acc[3]);
        acc[4] = fmaf(xv, w1.x, acc[4]);
        acc[5] = fmaf(xv, w1.y, acc[5]);
        acc[6] = fmaf(xv, w1.z, acc[6]);
        acc[7] = fmaf(xv, w1.w, acc[7]);
    }

    const float di = dinv[n0 + nl];
    union { uint4 u; __half2 h[4]; } pk;
    pk.h[0] = __floats2half2_rn(acc[0] * di, acc[1] * di);
    pk.h[1] = __floats2half2_rn(acc[2] * di, acc[3] * di);
    pk.h[2] = __floats2half2_rn(acc[4] * di, acc[5] * di);
    pk.h[3] = __floats2half2_rn(acc[6] * di, acc[7] * di);
    *(uint4*)(Hs + (size_t)(n0 + nl) * 64 + cg * 8) = pk.u;
}

// ------- aggregate: out = relu(dinv[d]*(sum_in w*Hs[src] + Hs[d]) + b) -------
// 1 wave (64 lanes) per dst node, lane = feature; 4 nodes per 256-thread block.

__global__ __launch_bounds__(256) void k_agg(const __half* __restrict__ Hs,
                                             const int* __restrict__ rowptr,
                                             const int2* __restrict__ csr,
                                             const float* __restrict__ dinv,
                                             const float* __restrict__ b,
                                             float* __restrict__ out, int n) {
    const int node = blockIdx.x * 4 + (threadIdx.x >> 6);
    const int j = threadIdx.x & 63;
    if (node >= n) return;
    const int p0 = rowptr[node];
    const int p1 = rowptr[node + 1];
    float acc = __half2float(Hs[(size_t)node * 64 + j]);  // self-loop (weight 1)
    int p = p0;
    for (; p + 3 < p1; p += 4) {
        const int2 c0 = csr[p];
        const int2 c1 = csr[p + 1];
        const int2 c2 = csr[p + 2];
        const int2 c3 = csr[p + 3];
        const float h0 = __half2float(Hs[(size_t)c0.x * 64 + j]);
        const float h1 = __half2float(Hs[(size_t)c1.x * 64 + j]);
        const float h2 = __half2float(Hs[(size_t)c2.x * 64 + j]);
        const float h3 = __half2float(Hs[(size_t)c3.x * 64 + j]);
        acc = fmaf(__int_as_float(c0.y), h0, acc);
        acc = fmaf(__int_as_float(c1.y), h1, acc);
        acc = fmaf(__int_as_float(c2.y), h2, acc);
        acc = fmaf(__int_as_float(c3.y), h3, acc);
    }
    for (; p < p1; ++p) {
        const int2 c = csr[p];
        acc = fmaf(__int_as_float(c.y), __half2float(Hs[(size_t)c.x * 64 + j]), acc);
    }
    out[(size_t)node * 64 + j] = fmaxf(fmaf(dinv[node], acc, b[j]), 0.f);
}

// ---------------- pooling: accumulate per-graph sums ----------------

__device__ __forceinline__ int lower_bound_i(const int* __restrict__ a, int n, int v) {
    int lo = 0, hi = n;
    while (lo < hi) {
        int mid = (lo + hi) >> 1;
        if (a[mid] < v) lo = mid + 1; else hi = mid;
    }
    return lo;
}

__global__ __launch_bounds__(256) void k_pool_add(const float* __restrict__ xl,
                                                  const int* __restrict__ batch,
                                                  float* __restrict__ pooled, int n) {
    const int g = blockIdx.x;
    const int tid = threadIdx.x;
    const int start = lower_bound_i(batch, n, g);
    const int end = lower_bound_i(batch, n, g + 1);

    const int j = tid & 63;
    const int q = tid >> 6;  // 0..3
    float s = 0.f;
    for (int nn = start + q; nn < end; nn += 4) {
        s += xl[(size_t)nn * 64 + j];
    }
    __shared__ float red[4][64];
    red[q][j] = s;
    __syncthreads();
    if (tid < 64) {
        pooled[g * 64 + j] += red[0][j] + red[1][j] + red[2][j] + red[3][j];
    }
}

// ---------------- head: logits = pooled/(3*cnt) @ Wl + bl ; softmax ----------------

__global__ __launch_bounds__(256) void k_head(const float* __restrict__ pooled,
                                              const int* __restrict__ batch,
                                              const float* __restrict__ Wl,
                                              const float* __restrict__ bl,
                                              float* __restrict__ out, int n) {
    __shared__ float Wls[64 * 10];
    __shared__ float bls[10];
    const int tid = threadIdx.x;
    for (int i = tid; i < 640; i += 256) Wls[i] = Wl[i];
    if (tid < 10) bls[tid] = bl[tid];
    __syncthreads();

    const int g = tid;  // one thread per graph
    const int start = lower_bound_i(batch, n, g);
    const int end = lower_bound_i(batch, n, g + 1);
    const int cnt = end - start;
    const float scale = 1.0f / (3.0f * (float)(cnt < 1 ? 1 : cnt));

    float p[10];
#pragma unroll
    for (int j = 0; j < 10; ++j) p[j] = bls[j];
    for (int k = 0; k < 64; ++k) {
        const float pv = pooled[g * 64 + k] * scale;
#pragma unroll
        for (int j = 0; j < 10; ++j) p[j] = fmaf(pv, Wls[k * 10 + j], p[j]);
    }
    float m = p[0];
#pragma unroll
    for (int j = 1; j < 10; ++j) m = fmaxf(m, p[j]);
    float sum = 0.f;
#pragma unroll
    for (int j = 0; j < 10; ++j) { p[j] = expf(p[j] - m); sum += p[j]; }
    const float inv = 1.f / sum;
#pragma unroll
    for (int j = 0; j < 10; ++j) out[g * 10 + j] = p[j] * inv;
}

// ---------------- launcher ----------------

extern "C" void kernel_launch(void* const* d_in, const int* in_sizes, int n_in,
                              void* d_out, int out_size, void* d_ws, size_t ws_size,
                              hipStream_t stream) {
    const float* x  = (const float*)d_in[0];
    const float* ew = (const float*)d_in[1];
    const float* W1 = (const float*)d_in[2];
    const float* b1 = (const float*)d_in[3];
    const float* W2 = (const float*)d_in[4];
    const float* b2 = (const float*)d_in[5];
    const float* W3 = (const float*)d_in[6];
    const float* b3 = (const float*)d_in[7];
    const float* Wl = (const float*)d_in[8];
    const float* bl = (const float*)d_in[9];
    const int* eidx  = (const int*)d_in[10];
    const int* batch = (const int*)d_in[11];
    const int* src = eidx;
    const int* dst = eidx + N_EDGES;

    // workspace layout (all offsets 16B aligned)
    float* ws = (float*)d_ws;
    float* dinv     = ws;                               // N
    int*   cnt      = (int*)(dinv + N_NODES);           // N
    int*   pos      = cnt + N_NODES;                    // E
    int*   rowptr   = pos + N_EDGES;                    // N+16
    int*   bsum     = rowptr + N_NODES + 16;            // 256
    int2*  csr      = (int2*)(bsum + 256);              // E (8B each)
    __half* Hs      = (__half*)(csr + N_EDGES);         // 64N halves
    float* A        = (float*)(Hs + (size_t)64 * N_NODES);  // 64N
    float* B        = A + (size_t)64 * N_NODES;         // 64N
    float* pooled   = B + (size_t)64 * N_NODES;         // 256*64

    float* outf = (float*)d_out;

    hipMemsetAsync(cnt, 0, N_NODES * sizeof(int), stream);
    hipMemsetAsync(pooled, 0, N_GRAPHS * F_SIZE * sizeof(float), stream);

    // ---- CSR build ----
    k_cnt_pos<<<(N_EDGES + 255) / 256, 256, 0, stream>>>(dst, cnt, pos, N_EDGES);
    const int nb = (N_NODES + 1023) / 1024;  // 98
    k_scan_local<<<nb, 256, 0, stream>>>(cnt, rowptr, bsum, N_NODES);
    k_scan_bsum<<<1, 64, 0, stream>>>(bsum, nb);
    k_scan_finish<<<(N_NODES + 255) / 256, 256, 0, stream>>>(rowptr, bsum, N_NODES, N_EDGES);
    k_csr_fill<<<(N_EDGES + 255) / 256, 256, 0, stream>>>(src, dst, ew, rowptr, pos, csr, N_EDGES);
    k_degsum<<<(N_NODES + 255) / 256, 256, 0, stream>>>(csr, rowptr, dinv, N_NODES);

    const int nagg = (N_NODES + 3) / 4;

    // layer 1
    k_gemm<128><<<N_NODES / 32, 256, 0, stream>>>(x, W1, dinv, Hs, N_NODES);
    k_agg<<<nagg, 256, 0, stream>>>(Hs, rowptr, csr, dinv, b1, A, N_NODES);
    k_pool_add<<<N_GRAPHS, 256, 0, stream>>>(A, batch, pooled, N_NODES);
    // layer 2
    k_gemm<64><<<N_NODES / 32, 256, 0, stream>>>(A, W2, dinv, Hs, N_NODES);
    k_agg<<<nagg, 256, 0, stream>>>(Hs, rowptr, csr, dinv, b2, B, N_NODES);
    k_pool_add<<<N_GRAPHS, 256, 0, stream>>>(B, batch, pooled, N_NODES);
    // layer 3
    k_gemm<64><<<N_NODES / 32, 256, 0, stream>>>(B, W3, dinv, Hs, N_NODES);
    k_agg<<<nagg, 256, 0, stream>>>(Hs, rowptr, csr, dinv, b3, A, N_NODES);
    k_pool_add<<<N_GRAPHS, 256, 0, stream>>>(A, batch, pooled, N_NODES);

    k_head<<<1, 256, 0, stream>>>(pooled, batch, Wl, bl, outf, N_NODES);
}